// Round 1
// 830.762 us; speedup vs baseline: 1.1569x; 1.1569x over previous
//
#include <hip/hip_runtime.h>

#define TT 2048
#define SS 128
#define DMAXX 128
#define NBATCH 64

typedef float f2 __attribute__((ext_vector_type(2)));

__device__ __forceinline__ float fexp2(float x){ return __builtin_amdgcn_exp2f(x); }
__device__ __forceinline__ float flog2(float x){ return __builtin_amdgcn_logf(x); }
__device__ __forceinline__ float frcp (float x){ return __builtin_amdgcn_rcpf(x); }
__device__ __forceinline__ f2 pkfma(f2 a, f2 b, f2 c){ return __builtin_elementwise_fma(a, b, c); }

template<int CTRL>
__device__ __forceinline__ float dppf(float x) {
    int i = __float_as_int(x);
    return __int_as_float(__builtin_amdgcn_update_dpp(i, i, CTRL, 0xF, 0xF, false));
}
#define DPP_XOR1   0xB1  // quad_perm(1,0,3,2)
#define DPP_XOR2   0x4E  // quad_perm(2,3,0,1)
#define DPP_SHUP1  0x90  // quad_perm(0,0,1,2)
#define DPP_ROR4   0x124
#define DPP_ROR8   0x128
#define DPP_BC15   0x142
#define DPP_BC31   0x143

constexpr float LOG2E = 1.4426950408889634f;
constexpr float LN2   = 0.6931471805599453f;

// Layout (R4/R7, 0 bank conflicts): j = tid>>2 (state), q = tid&3 (lag chunk).
// Thread (j,q) owns ring lags [32q+1..32q+32] (register-renamed), eA[32q..][j], eD[j][32q..].
//
// G-factored ("raw") ring: slot values are stored divided by the cumulative
// per-state emission/renorm scale G_t.  Per step: G *= g (g = exp(logB), with
// renorm 1/m folded in every 8th step).  dur_abs = dsP_raw * G; fresh insert
// raw = tp * rcp(G_prev); chunk-to-chunk carry moves with NO multiply.
// Ring is rebased (rp *= G; G = 1) once per 32-step window for fp32 range.
//
// Software pipeline: the ring-insert + raw duration-sum for step t+1 run in
// the TAIL of step t (register-only, pre-barrier) — they overlap the
// ds_write/barrier/ds_read latency.  Post-barrier work is just trans + join.
struct State {
    f2    rp[16];   // raw ring: slot s (see tail) holds entry/G at its insert time
    f2    eAp[16];  // (eA[2k], eA[2k+1]), eA[i]=exp(A[32q+i][j])
    f2    eDp[32];  // pair table: eDp[w] = (eD[w], eD[(w+1)&31]), eD[k]=exp(D[j][32q+k])
    float eD0;      // exp(D[j][0]) — lag-1 weight for the fresh slot
    float pf[4];    // logB prefetch, distance 4
    const float* pfp;  // prefetch pointer (lb + (t+4)*SS), advanced SS/step
    float C2;       // accumulated log2(m)
    float e_pi;
    float G;        // cumulative scale within current 32-step rebase window
    float dsP;      // raw duration-sum for the upcoming step (computed in prev tail)
};

struct Ctx {
    const float4* up0; const float4* up1;  // ua chunk reads (broadcast, stride-36 chunks)
    const f2*     wmp;                     // renorm read: pair (wm[2q], wm[2q+1])
    float* uaw0; float* uaw1;              // U write (q==0 lanes)
    float* wmwp;                           // wave-max write (lane 63)
    bool q0, l63;
};

template<int PHI>
__device__ __forceinline__ void hsmm_step(State& st, const Ctx& c, int tb)
{
    constexpr int  rho    = 31 - PHI;               // this step's fresh slot (inserted in prev tail)
    constexpr int  rhoN   = 31 - ((PHI + 1) & 31);  // slot to insert for NEXT step (tail)
    constexpr int  pb     = (PHI + 1) & 1;
    constexpr int  wb     = PHI & 1;
    constexpr bool DO_WM  = ((PHI & 7) == 6);
    constexpr bool DO_RN  = ((PHI & 7) == 7);
    constexpr bool REBASE = (PHI == 31);
    const int t = tb + PHI;

    // ---- issue all ua loads up front (8 x b128, broadcast, conflict-free) ----
    const float4* up = pb ? c.up1 : c.up0;
    float4 v[8];
#pragma unroll
    for (int k = 0; k < 8; ++k) v[k] = up[k];

    // ---- step multiplier g and scale bookkeeping ----
    float xB = st.pf[PHI & 3];                 // logB[t]
    if (t + 4 < TT) st.pf[PHI & 3] = st.pfp[0];
    st.pfp += SS;
    float g = fexp2(xB * LOG2E);
    if constexpr (DO_RN) {
        f2 wv = *c.wmp;                        // 2 of 8 wave maxes (written at PHI-1)
        float m = fmaxf(wv.x, wv.y);
        m = fmaxf(m, dppf<DPP_XOR1>(m));
        m = fmaxf(m, dppf<DPP_XOR2>(m));       // max over all 8 waves
        st.C2 += flog2(m);
        g *= frcp(m);
    }
    float rG = frcp(st.G);                     // 1/G_{t-1}, for the raw fresh insert
    float Gn = st.G * g;                       // G_t
    st.G = Gn;

    // ---- trans: Etrans[j] = sum_i U_prev[i]*eA[i][j] over chunk q, quad-reduce ----
    f2 a0, a1, a2, a3;
    {
        f2 u;
        u = (f2){v[0].x, v[0].y}; a0 = u * st.eAp[0];
        u = (f2){v[0].z, v[0].w}; a1 = u * st.eAp[1];
        u = (f2){v[1].x, v[1].y}; a2 = u * st.eAp[2];
        u = (f2){v[1].z, v[1].w}; a3 = u * st.eAp[3];
#pragma unroll
        for (int kk = 2; kk < 8; kk += 2) {
            u = (f2){v[kk].x,     v[kk].y};     a0 = pkfma(u, st.eAp[2 * kk],     a0);
            u = (f2){v[kk].z,     v[kk].w};     a1 = pkfma(u, st.eAp[2 * kk + 1], a1);
            u = (f2){v[kk + 1].x, v[kk + 1].y}; a2 = pkfma(u, st.eAp[2 * kk + 2], a2);
            u = (f2){v[kk + 1].z, v[kk + 1].w}; a3 = pkfma(u, st.eAp[2 * kk + 3], a3);
        }
    }
    f2 asum = (a0 + a1) + (a2 + a3);
    float tp = asum.x + asum.y;
    tp += dppf<DPP_XOR1>(tp);
    tp += dppf<DPP_XOR2>(tp);                  // full Etrans[j], quad-uniform
    if constexpr (PHI == 0) { if (tb == 0) tp = st.e_pi; }   // t==0: entry = pi

    // ---- join: U = G*raw_dur(lags>=2) + fresh lag-1 term; patch fresh slot ----
    float U = fmaf(tp * g, st.eD0, st.dsP * Gn);
    if (c.q0) {
        float fr = tp * rG;                    // raw entry value = entry[t]/G_{t-1}
        if constexpr (rho & 1) st.rp[rho >> 1].y = fr;
        else                   st.rp[rho >> 1].x = fr;
        *(wb ? c.uaw1 : c.uaw0) = U;
    }

    // ---- wave max only on pre-renorm steps ----
    if constexpr (DO_WM) {
        float wm = U;
        wm = fmaxf(wm, dppf<DPP_ROR4>(wm));
        wm = fmaxf(wm, dppf<DPP_ROR8>(wm));
        wm = fmaxf(wm, dppf<DPP_BC15>(wm));
        wm = fmaxf(wm, dppf<DPP_BC31>(wm));    // lane63 = max over wave's 16 states
        if (c.l63) *c.wmwp = wm;
    }

    // ---- rebase once per 32-step window (fp32 range control) ----
    if constexpr (REBASE) {
        f2 GG = {Gn, Gn};
#pragma unroll
        for (int m2 = 0; m2 < 16; ++m2) st.rp[m2] = st.rp[m2] * GG;
        st.G = 1.f;
    }

    // ---- TAIL (pre-barrier, register-only): insert + raw dur-sum for step t+1 ----
    float rold;
    if constexpr (rhoN & 1) rold = st.rp[rhoN >> 1].y; else rold = st.rp[rhoN >> 1].x;
    float car = dppf<DPP_SHUP1>(rold);         // lag-neighbor's expiring slot (same j, same G)
    float ins = c.q0 ? 0.f : car;              // raw carry: NO multiply; q0 patched next step
    if constexpr (rhoN & 1) st.rp[rhoN >> 1].y = ins;
    else                    st.rp[rhoN >> 1].x = ins;

    f2 q0a = {0.f, 0.f}, q1a = {0.f, 0.f}, q2a = {0.f, 0.f}, q3a = {0.f, 0.f};
#pragma unroll
    for (int m2 = 0; m2 < 16; m2 += 4) {
        q0a = pkfma(st.rp[m2],     st.eDp[(2 * m2 + PHI + 2) & 31], q0a);
        q1a = pkfma(st.rp[m2 + 1], st.eDp[(2 * m2 + PHI + 4) & 31], q1a);
        q2a = pkfma(st.rp[m2 + 2], st.eDp[(2 * m2 + PHI + 6) & 31], q2a);
        q3a = pkfma(st.rp[m2 + 3], st.eDp[(2 * m2 + PHI + 8) & 31], q3a);
    }
    f2 qs = (q0a + q1a) + (q2a + q3a);
    float ds = qs.x + qs.y;
    ds += dppf<DPP_XOR1>(ds);
    ds += dppf<DPP_XOR2>(ds);                  // raw lags 2..128 for t+1 (quad-uniform)
    st.dsP = ds;

    asm volatile("s_waitcnt lgkmcnt(0)\n\ts_barrier" ::: "memory");
}

__launch_bounds__(512, 2)
__global__ void hsmm_fwd_kernel(const float* __restrict__ logB,
                                const float* __restrict__ pi,
                                const float* __restrict__ A,
                                const float* __restrict__ D,
                                float* __restrict__ out)
{
    const int b   = blockIdx.x;
    const int tid = threadIdx.x;
    const int l   = tid & 63;
    const int w   = tid >> 6;
    const int j   = tid >> 2;
    const int q   = tid & 3;

    // chunk c at c*36 floats: 16B-aligned, bank-spread (R4/R7: 0 conflicts)
    __shared__ __align__(16) float ua[2][4 * 36];
    __shared__ __align__(16) float wmaxf[8];

    State st;
#pragma unroll
    for (int k = 0; k < 16; ++k) {
        st.eAp[k].x = fexp2(A[(q * 32 + 2 * k)     * SS + j] * LOG2E);
        st.eAp[k].y = fexp2(A[(q * 32 + 2 * k + 1) * SS + j] * LOG2E);
    }
    {
        float eD[32];
#pragma unroll
        for (int k = 0; k < 32; ++k)
            eD[k] = fexp2(D[j * DMAXX + q * 32 + k] * LOG2E);
#pragma unroll
        for (int wdx = 0; wdx < 32; ++wdx) {
            st.eDp[wdx].x = eD[wdx];
            st.eDp[wdx].y = eD[(wdx + 1) & 31];
        }
    }
#pragma unroll
    for (int k = 0; k < 16; ++k) st.rp[k] = (f2){0.f, 0.f};
    st.eD0  = fexp2(D[j * DMAXX] * LOG2E);
    st.C2   = 0.f;
    st.e_pi = fexp2(pi[j] * LOG2E);
    st.G    = 1.f;
    st.dsP  = 0.f;   // t=0 has no lag>=2 mass

    const float* __restrict__ lb = logB + ((size_t)b * TT) * SS + j;
#pragma unroll
    for (int k = 0; k < 4; ++k) st.pf[k] = lb[(size_t)k * SS];
    st.pfp = lb + (size_t)4 * SS;

    Ctx c;
    c.up0  = (const float4*)&ua[0][q * 36];
    c.up1  = (const float4*)&ua[1][q * 36];
    c.wmp  = (const f2*)&wmaxf[2 * q];     // quad covers all 8 wave maxes
    c.q0   = (q == 0);
    c.l63  = (l == 63);
    c.uaw0 = &ua[0][(j >> 5) * 36 + (j & 31)];
    c.uaw1 = &ua[1][(j >> 5) * 36 + (j & 31)];
    c.wmwp = &wmaxf[w];

    for (int tb = 0; tb < TT; tb += 32) {
        hsmm_step< 0>(st, c, tb); hsmm_step< 1>(st, c, tb);
        hsmm_step< 2>(st, c, tb); hsmm_step< 3>(st, c, tb);
        hsmm_step< 4>(st, c, tb); hsmm_step< 5>(st, c, tb);
        hsmm_step< 6>(st, c, tb); hsmm_step< 7>(st, c, tb);
        hsmm_step< 8>(st, c, tb); hsmm_step< 9>(st, c, tb);
        hsmm_step<10>(st, c, tb); hsmm_step<11>(st, c, tb);
        hsmm_step<12>(st, c, tb); hsmm_step<13>(st, c, tb);
        hsmm_step<14>(st, c, tb); hsmm_step<15>(st, c, tb);
        hsmm_step<16>(st, c, tb); hsmm_step<17>(st, c, tb);
        hsmm_step<18>(st, c, tb); hsmm_step<19>(st, c, tb);
        hsmm_step<20>(st, c, tb); hsmm_step<21>(st, c, tb);
        hsmm_step<22>(st, c, tb); hsmm_step<23>(st, c, tb);
        hsmm_step<24>(st, c, tb); hsmm_step<25>(st, c, tb);
        hsmm_step<26>(st, c, tb); hsmm_step<27>(st, c, tb);
        hsmm_step<28>(st, c, tb); hsmm_step<29>(st, c, tb);
        hsmm_step<30>(st, c, tb); hsmm_step<31>(st, c, tb);
    }

    // epilogue: out[b] = (C2 + log2(sum_j U_{T-1}[j])) * ln2 ;  (T-1)&1 == 1
    if (tid == 0) {
        float s = 0.f;
        for (int i = 0; i < SS; ++i) s += ua[1][(i >> 5) * 36 + (i & 31)];
        out[b] = (st.C2 + flog2(s)) * LN2;
    }
}

extern "C" void kernel_launch(void* const* d_in, const int* in_sizes, int n_in,
                              void* d_out, int out_size, void* d_ws, size_t ws_size,
                              hipStream_t stream) {
    const float* logB = (const float*)d_in[0];   // (64, 2048, 128) f32
    const float* pi   = (const float*)d_in[1];   // (128,) f32
    const float* A    = (const float*)d_in[2];   // (128, 128) f32
    const float* D    = (const float*)d_in[3];   // (128, 128) f32
    float* out        = (float*)d_out;           // (64,) f32
    hipLaunchKernelGGL(hsmm_fwd_kernel, dim3(NBATCH), dim3(512), 0, stream,
                       logB, pi, A, D, out);
}